// Round 1
// baseline (407.777 us; speedup 1.0000x reference)
//
#include <hip/hip_runtime.h>
#include <math.h>

#define BATCH 16384
#define NB 8
#define NT 256

// ---------------- path metadata ----------------
// 15 paths: l3=0: (0,0,0),(1,1,0),(2,2,0)
//           l3=1: (0,1,1),(1,0,1),(1,1,1),(1,2,1),(2,1,1),(2,2,1)
//           l3=2: (0,2,2),(1,1,2),(1,2,2),(2,0,2),(2,1,2),(2,2,2)
__device__ const int P_CGOFF[15] = {0,1,10,35,44,53,80,125,170,245,270,315,390,415,490};
__device__ const int P_D1[15]    = {1,3,5,1,3,3,3,5,5,1,3,3,5,5,5};
__device__ const int P_D2[15]    = {1,3,5,3,1,3,5,3,5,5,3,5,1,3,5};
__device__ const int P_D3[15]    = {1,1,1,3,3,3,3,3,3,5,5,5,5,5,5};
__device__ const int P_L1[15]    = {0,1,2,0,1,1,1,2,2,0,1,1,2,2,2};
__device__ const int P_L2[15]    = {0,1,2,1,0,1,2,1,2,2,1,2,0,1,2};
__device__ const int P_L3[15]    = {0,0,0,1,1,1,1,1,1,2,2,2,2,2,2};
__device__ const int P_TSTART[15]= {0,1,4,9,12,21,30,39,54,69,74,89,104,129,154}; // cumsum of d1*d3
__device__ const int P_YOFF[15]  = {0,1,4,1,0,1,4,1,4,4,1,4,0,1,4};

__device__ const int G_NSEG[3] = {3,6,6};
__device__ const int G_SEGP[3][6] = {{0,1,2,0,0,0},{3,4,5,6,7,8},{9,10,11,12,13,14}};
__device__ const int G_U0[3][7] = {{0,128,192,224,224,224,224},
                                   {0,128,192,256,320,352,384},
                                   {0,128,192,256,288,320,352}};
__device__ const int G_K[3]  = {224,384,352};
__device__ const int G_N[3]  = {128,64,32};
__device__ const int G_D3[3] = {1,3,5};
__device__ const int G_OB[3] = {0,128,320};
__device__ const int G_CK[3] = {224,192,176};   // K-chunk sizes (Zs <= 7040 floats)
__device__ const int G_NCH[3]= {1,2,2};
__device__ const int XOFF_L1[3] = {0,128,320};

// ---------------- CG setup kernel (exact e3nn convention) ----------------
__device__ double dfact(int n){ double r=1.0; for(int i=2;i<=n;++i) r*=(double)i; return r; }

__device__ double su2_cg(int j1,int j2,int j3,int m1,int m2,int m3){
  if (m1+m2 != m3) return 0.0;
  double pref = sqrt((double)(2*j3+1)*dfact(j1+j2-j3)*dfact(j1-j2+j3)*dfact(-j1+j2+j3)/dfact(j1+j2+j3+1));
  pref *= sqrt(dfact(j3+m3)*dfact(j3-m3)*dfact(j1-m1)*dfact(j1+m1)*dfact(j2-m2)*dfact(j2+m2));
  double s=0.0;
  for(int v=0;v<=j1+j2-j3;++v){
    int a=j1+j2-j3-v, b=j1-m1-v, c=j2+m2-v, d=j3-j2+m1+v, e=j3-j1-m2+v;
    if(a<0||b<0||c<0||d<0||e<0) continue;
    double term = 1.0/(dfact(v)*dfact(a)*dfact(b)*dfact(c)*dfact(d)*dfact(e));
    s += (v&1)? -term : term;
  }
  return pref*s;
}

// Q_l[r][c] (real->complex change of basis, including (-i)^l factor)
__device__ void qval(int l,int r,int c,double* qr,double* qi){
  int m = r - l;
  const double is2 = 0.70710678118654752440;
  double br=0.0, bi=0.0;
  if (m<0){
    if (c == l - m) br = is2;        // col l+|m|
    else if (c == l + m) bi = -is2;  // col l-|m|
  } else if (m==0){
    if (c==l) br = 1.0;
  } else {
    double sg = (m&1)? -1.0 : 1.0;
    if (c == l + m) br = sg*is2;
    else if (c == l - m) bi = sg*is2;
  }
  if (l==1){ double nr = bi, ni = -br; br=nr; bi=ni; }  // *( -i )
  else if (l==2){ br=-br; bi=-bi; }                     // *( -i )^2
  *qr=br; *qi=bi;
}

__global__ void cg_setup(float* __restrict__ cg){
  int tid = blockIdx.x*blockDim.x + threadIdx.x;
  if (tid >= 615) return;
  int p = 0;
  while (p+1 < 15 && tid >= P_CGOFF[p+1]) ++p;
  int r = tid - P_CGOFF[p];
  int d2 = P_D2[p], d3 = P_D3[p];
  int i1 = r/(d2*d3); int rem = r - i1*(d2*d3); int i2 = rem/d3; int i3 = rem - i2*d3;
  int l1=P_L1[p], l2=P_L2[p], l3=P_L3[p];
  double acc = 0.0;
  for (int i=0;i<=2*l1;++i){
    for (int k=0;k<=2*l2;++k){
      int n = i + k - l1 - l2 + l3;      // m3 = m1+m2
      if (n<0 || n>2*l3) continue;
      double c = su2_cg(l1,l2,l3, i-l1, k-l2, n-l3);
      if (c==0.0) continue;
      double q1r,q1i,q2r,q2i,q3r,q3i;
      qval(l1,i,i1,&q1r,&q1i);
      qval(l2,k,i2,&q2r,&q2i);
      qval(l3,n,i3,&q3r,&q3i);
      q3i = -q3i;                        // conj(Q3)
      double ar = q1r*q2r - q1i*q2i;
      double ai = q1r*q2i + q1i*q2r;
      acc += (ar*q3r - ai*q3i)*c;        // real part only (imag cancels)
    }
  }
  cg[tid] = (float)acc;
}

// ---------------- fused TP + Linear kernel ----------------
__global__ __launch_bounds__(NT) void tp_linear(
    const float* __restrict__ x, const float* __restrict__ y,
    const float* __restrict__ W0, const float* __restrict__ W1,
    const float* __restrict__ W2, const float* __restrict__ cg,
    float* __restrict__ out)
{
  __shared__ float xs[NB][484];    // 480 + 4 pad (bank decorrelate)
  __shared__ float ys[NB][12];
  __shared__ float Ts[1432];       // 179 entries x 8 batches
  __shared__ float Zs[7040];       // K-chunk x d3 x 8 batches

  const int tid = threadIdx.x;
  const int b0 = blockIdx.x * NB;

  // ---- load x (float4) and y ----
  {
    const float4* x4 = (const float4*)(x + (size_t)b0*480);
    for (int idx = tid; idx < NB*120; idx += NT){
      int b = idx/120, c = idx - b*120;
      float4 v = x4[b*120 + c];
      *(float4*)&xs[b][c*4] = v;
    }
    for (int idx = tid; idx < NB*9; idx += NT){
      int b = idx/9, c = idx - b*9;
      ys[b][c] = y[(size_t)(b0+b)*9 + c];
    }
  }
  __syncthreads();

  // ---- T phase: T_p[b][i1][i3] = sum_i2 cg[i1,i2,i3]*y[b,i2] ----
  for (int idx = tid; idx < 179*8; idx += NT){
    int e = idx >> 3, b = idx & 7;
    int p = 0; while (p+1 < 15 && e >= P_TSTART[p+1]) ++p;
    int r = e - P_TSTART[p];
    int d3 = P_D3[p], d2 = P_D2[p];
    int i1 = r/d3, i3 = r - i1*d3;
    const float* cgp = cg + P_CGOFF[p] + (i1*d2)*d3 + i3;
    const float* yb  = &ys[b][P_YOFF[p]];
    float t = 0.f;
    for (int i2=0;i2<d2;++i2) t += cgp[i2*d3]*yb[i2];
    Ts[e*8 + b] = t;
  }
  __syncthreads();

  // ---- per output-l group ----
  for (int g = 0; g < 3; ++g){
    const int K = G_K[g], N = G_N[g], d3 = G_D3[g];
    const int ck = G_CK[g], nch = G_NCH[g];
    const float* Wg = (g==0)? W0 : (g==1)? W1 : W2;

    const bool act = (tid < N*d3);
    int v = 0, i3o = 0;
    if (act){ v = tid / d3; i3o = tid - v*d3; }
    float acc[8] = {0.f,0.f,0.f,0.f,0.f,0.f,0.f,0.f};

    for (int c = 0; c < nch; ++c){
      const int u_lo = c*ck;
      const int Kc = ((u_lo + ck) < K ? ck : (K - u_lo));

      // Phase A: build Z chunk in LDS
      for (int idx = tid; idx < Kc*NB; idx += NT){
        int uu = idx >> 3, b = idx & 7;
        int u = u_lo + uu;
        int s = 0;
        while (s+1 < G_NSEG[g] && u >= G_U0[g][s+1]) ++s;
        int pth = G_SEGP[g][s];
        int u1 = u - G_U0[g][s];
        int d1 = P_D1[pth];
        const float* xb = &xs[b][XOFF_L1[P_L1[pth]] + u1*d1];
        const float* tb = &Ts[P_TSTART[pth]*8 + b];
        float xr[5];
        for (int i1=0;i1<d1;++i1) xr[i1] = xb[i1];
        for (int i3=0;i3<d3;++i3){
          float z = 0.f;
          for (int i1=0;i1<d1;++i1) z += xr[i1]*tb[(i1*d3+i3)*8];
          Zs[(uu*d3+i3)*8 + b] = z;
        }
      }
      __syncthreads();

      // Phase B: GEMM chunk, 8-batch register accumulate
      if (act){
        const float* Wc = Wg + (size_t)u_lo*N + v;
        #pragma unroll 4
        for (int uu = 0; uu < Kc; ++uu){
          float w = Wc[uu*N];
          const float* zp = &Zs[(uu*d3 + i3o)*8];
          float4 zlo = *(const float4*)(zp);
          float4 zhi = *(const float4*)(zp+4);
          acc[0] += zlo.x*w; acc[1] += zlo.y*w; acc[2] += zlo.z*w; acc[3] += zlo.w*w;
          acc[4] += zhi.x*w; acc[5] += zhi.y*w; acc[6] += zhi.z*w; acc[7] += zhi.w*w;
        }
      }
      __syncthreads();
    }

    if (act){
      const float sc = rsqrtf((float)K);
      const int ob = G_OB[g] + v*d3 + i3o;
      for (int b=0;b<NB;++b)
        out[(size_t)(b0+b)*480 + ob] = acc[b]*sc;
    }
    // Zs reuse across g is protected by the chunk-loop trailing barrier
  }
}

extern "C" void kernel_launch(void* const* d_in, const int* in_sizes, int n_in,
                              void* d_out, int out_size, void* d_ws, size_t ws_size,
                              hipStream_t stream)
{
  const float* x  = (const float*)d_in[0];
  const float* y  = (const float*)d_in[1];
  const float* W0 = (const float*)d_in[2];
  const float* W1 = (const float*)d_in[3];
  const float* W2 = (const float*)d_in[4];
  float* out = (float*)d_out;
  float* cg  = (float*)d_ws;   // 615 floats of CG coefficients

  hipLaunchKernelGGL(cg_setup, dim3(3), dim3(256), 0, stream, cg);
  hipLaunchKernelGGL(tp_linear, dim3(BATCH/NB), dim3(NT), 0, stream,
                     x, y, W0, W1, W2, cg, out);
}

// Round 2
// 301.990 us; speedup vs baseline: 1.3503x; 1.3503x over previous
//
#include <hip/hip_runtime.h>
#include <math.h>
#include <stdint.h>

#define NBATCH 16384
#define NB 32
#define NT 256

// ---------------- path metadata (validated in round 1) ----------------
__device__ const int P_CGOFF[15] = {0,1,10,35,44,53,80,125,170,245,270,315,390,415,490};
__device__ const int P_D2[15]    = {1,3,5,3,1,3,5,3,5,5,3,5,1,3,5};
__device__ const int P_D3[15]    = {1,1,1,3,3,3,3,3,3,5,5,5,5,5,5};
__device__ const int P_TSTART[15]= {0,1,4,9,12,21,30,39,54,69,74,89,104,129,154};
__device__ const int P_YOFF[15]  = {0,1,4,1,0,1,4,1,4,4,1,4,0,1,4};

// ---------------- CG setup kernel (exact e3nn convention, validated) ----------------
__device__ double dfact(int n){ double r=1.0; for(int i=2;i<=n;++i) r*=(double)i; return r; }

__device__ double su2_cg(int j1,int j2,int j3,int m1,int m2,int m3){
  if (m1+m2 != m3) return 0.0;
  double pref = sqrt((double)(2*j3+1)*dfact(j1+j2-j3)*dfact(j1-j2+j3)*dfact(-j1+j2+j3)/dfact(j1+j2+j3+1));
  pref *= sqrt(dfact(j3+m3)*dfact(j3-m3)*dfact(j1-m1)*dfact(j1+m1)*dfact(j2-m2)*dfact(j2+m2));
  double s=0.0;
  for(int v=0;v<=j1+j2-j3;++v){
    int a=j1+j2-j3-v, b=j1-m1-v, c=j2+m2-v, d=j3-j2+m1+v, e=j3-j1-m2+v;
    if(a<0||b<0||c<0||d<0||e<0) continue;
    double term = 1.0/(dfact(v)*dfact(a)*dfact(b)*dfact(c)*dfact(d)*dfact(e));
    s += (v&1)? -term : term;
  }
  return pref*s;
}

__device__ const int CG_D1[15] = {1,3,5,1,3,3,3,5,5,1,3,3,5,5,5};
__device__ const int CG_L1[15] = {0,1,2,0,1,1,1,2,2,0,1,1,2,2,2};
__device__ const int CG_L2[15] = {0,1,2,1,0,1,2,1,2,2,1,2,0,1,2};
__device__ const int CG_L3[15] = {0,0,0,1,1,1,1,1,1,2,2,2,2,2,2};

__device__ void qval(int l,int r,int c,double* qr,double* qi){
  int m = r - l;
  const double is2 = 0.70710678118654752440;
  double br=0.0, bi=0.0;
  if (m<0){
    if (c == l - m) br = is2;
    else if (c == l + m) bi = -is2;
  } else if (m==0){
    if (c==l) br = 1.0;
  } else {
    double sg = (m&1)? -1.0 : 1.0;
    if (c == l + m) br = sg*is2;
    else if (c == l - m) bi = sg*is2;
  }
  if (l==1){ double nr = bi, ni = -br; br=nr; bi=ni; }
  else if (l==2){ br=-br; bi=-bi; }
  *qr=br; *qi=bi;
}

__global__ void cg_setup(float* __restrict__ cg){
  int tid = blockIdx.x*blockDim.x + threadIdx.x;
  if (tid >= 615) return;
  int p = 0;
  while (p+1 < 15 && tid >= P_CGOFF[p+1]) ++p;
  int r = tid - P_CGOFF[p];
  int d2 = P_D2[p], d3 = P_D3[p];
  int i1 = r/(d2*d3); int rem = r - i1*(d2*d3); int i2 = rem/d3; int i3 = rem - i2*d3;
  int l1=CG_L1[p], l2=CG_L2[p], l3=CG_L3[p];
  double acc = 0.0;
  for (int i=0;i<=2*l1;++i){
    for (int k=0;k<=2*l2;++k){
      int n = i + k - l1 - l2 + l3;
      if (n<0 || n>2*l3) continue;
      double c = su2_cg(l1,l2,l3, i-l1, k-l2, n-l3);
      if (c==0.0) continue;
      double q1r,q1i,q2r,q2i,q3r,q3i;
      qval(l1,i,i1,&q1r,&q1i);
      qval(l2,k,i2,&q2r,&q2i);
      qval(l3,n,i3,&q3r,&q3i);
      q3i = -q3i;
      double ar = q1r*q2r - q1i*q2i;
      double ai = q1r*q2i + q1i*q2r;
      acc += (ar*q3r - ai*q3i)*c;
    }
  }
  cg[tid] = (float)acc;
}

// ---------------- bf16 helpers ----------------
__device__ __forceinline__ uint32_t f2bf(float f){
  uint32_t u = __float_as_uint(f);
  return (u + 0x7fffu + ((u>>16)&1u)) >> 16;   // RNE
}
__device__ __forceinline__ float bflo(uint32_t u){ return __uint_as_float(u<<16); }
__device__ __forceinline__ float bfhi(uint32_t u){ return __uint_as_float(u & 0xffff0000u); }
__device__ __forceinline__ uint32_t pk2(float a, float b){ return (f2bf(b)<<16) | f2bf(a); }
__device__ __forceinline__ void unpack8(uint4 q, float* z){
  z[0]=bflo(q.x); z[1]=bfhi(q.x); z[2]=bflo(q.y); z[3]=bfhi(q.y);
  z[4]=bflo(q.z); z[5]=bfhi(q.z); z[6]=bflo(q.w); z[7]=bfhi(q.w);
}

template<int I> struct IC { static constexpr int v = I; };

// ---------------- per-group compile-time metadata ----------------
template<int G> struct GM;
template<> struct GM<0>{
  static constexpr int K=224,N=128,D3=1,VB=2,OB=0,NSEG=3,NCH=1;
  static constexpr int CKS[1]={224};
  static constexpr int U0[4]={0,128,192,224};
  static constexpr int D1S[3]={1,3,5};
  static constexpr int TS0[3]={0,1,4};
  static constexpr int XO[3]={0,128,320};
  static constexpr float SC = 0.066815310478f;   // 1/sqrt(224)
};
template<> struct GM<1>{
  static constexpr int K=384,N=64,D3=3,VB=4,OB=128,NSEG=6,NCH=4;
  static constexpr int CKS[4]={96,96,96,96};
  static constexpr int U0[7]={0,128,192,256,320,352,384};
  static constexpr int D1S[6]={1,3,3,3,5,5};
  static constexpr int TS0[6]={9,12,21,30,39,54};
  static constexpr int XO[6]={0,128,128,128,320,320};
  static constexpr float SC = 0.051031036308f;   // 1/sqrt(384)
};
template<> struct GM<2>{
  static constexpr int K=352,N=32,D3=5,VB=4,OB=320,NSEG=6,NCH=6;
  static constexpr int CKS[6]={60,60,60,60,60,52};
  static constexpr int U0[7]={0,128,192,256,288,320,352};
  static constexpr int D1S[6]={1,3,3,5,5,5};
  static constexpr int TS0[6]={69,74,89,104,129,154};
  static constexpr int XO[6]={0,128,128,320,320,320};
  static constexpr float SC = 0.053300179089f;   // 1/sqrt(352)
};

// ---------------- per-group fused TP(Z-build) + Linear ----------------
template<int G>
__device__ __forceinline__ void run_group(const float* __restrict__ Wg,
                                          float* __restrict__ out, int b0, int tid,
                                          const uint16_t* xs, const uint16_t* Tsh,
                                          uint16_t* Zs)
{
  using M = GM<G>;
  constexpr int D3 = M::D3, VB = M::VB, N = M::N;

  const int bg = tid & 3;                 // batch-group (8 batches each)
  const int i3 = (tid >> 2) % D3;
  const int vg = tid / (4*D3);
  const bool act = vg < N/VB;

  float acc[VB][8];
  #pragma unroll
  for (int j=0;j<VB;++j)
    #pragma unroll
    for (int k=0;k<8;++k) acc[j][k] = 0.f;

  int u0 = 0;
  for (int ch = 0; ch < M::NCH; ++ch){
    const int Kc = M::CKS[ch];

    // ---- Phase A: build Z chunk (bf16, [row=(uu*D3+i3)][32 batches]) ----
    for (int idx = tid; idx < Kc*4; idx += NT){
      const int uu = idx >> 2, tb = idx & 3;
      const int u = u0 + uu;
      int s = 0;
      #pragma unroll
      for (int t = 0; t < M::NSEG-1; ++t) s += (u >= M::U0[t+1]);
      const int u1 = u - M::U0[s];
      const int d1 = M::D1S[s];
      const int cb = M::XO[s] + u1*d1;
      const int ts = M::TS0[s];

      auto body = [&](auto D1T){
        constexpr int D1 = decltype(D1T)::v;
        float xv[D1][8];
        #pragma unroll
        for (int i1 = 0; i1 < D1; ++i1){
          uint4 q = *(const uint4*)&xs[(cb+i1)*32 + tb*8];
          unpack8(q, xv[i1]);
        }
        #pragma unroll
        for (int j3 = 0; j3 < D3; ++j3){
          float z[8] = {0.f,0.f,0.f,0.f,0.f,0.f,0.f,0.f};
          #pragma unroll
          for (int i1 = 0; i1 < D1; ++i1){
            uint4 tq = *(const uint4*)&Tsh[(ts + i1*D3 + j3)*40 + tb*8];
            float tv[8]; unpack8(tq, tv);
            #pragma unroll
            for (int k=0;k<8;++k) z[k] += xv[i1][k]*tv[k];
          }
          uint4 o;
          o.x = pk2(z[0],z[1]); o.y = pk2(z[2],z[3]);
          o.z = pk2(z[4],z[5]); o.w = pk2(z[6],z[7]);
          *(uint4*)&Zs[(uu*D3 + j3)*32 + tb*8] = o;
        }
      };
      if (d1 == 1) body(IC<1>{}); else if (d1 == 3) body(IC<3>{}); else body(IC<5>{});
    }
    __syncthreads();

    // ---- Phase B: register-accumulated GEMM chunk ----
    if (act){
      const float* wp = Wg + (size_t)u0*N + vg*VB;
      const uint16_t* zp = Zs + i3*32 + bg*8;
      #pragma unroll 2
      for (int uu = 0; uu < Kc; ++uu){
        uint4 zq = *(const uint4*)(zp + uu*(D3*32));
        float z[8]; unpack8(zq, z);
        float w[VB];
        if constexpr (VB == 4){
          float4 wv = *(const float4*)(wp + uu*N);
          w[0]=wv.x; w[1]=wv.y; w[2]=wv.z; w[3]=wv.w;
        } else {
          float2 wv = *(const float2*)(wp + uu*N);
          w[0]=wv.x; w[1]=wv.y;
        }
        #pragma unroll
        for (int j=0;j<VB;++j)
          #pragma unroll
          for (int k=0;k<8;++k) acc[j][k] += w[j]*z[k];
      }
    }
    __syncthreads();
    u0 += Kc;
  }

  if (act){
    #pragma unroll
    for (int j=0;j<VB;++j){
      const int col = M::OB + (vg*VB + j)*D3 + i3;
      #pragma unroll
      for (int k=0;k<8;++k)
        out[(size_t)(b0 + bg*8 + k)*480 + col] = acc[j][k]*M::SC;
    }
  }
}

// ---------------- main fused kernel ----------------
__global__ __launch_bounds__(NT) void tp_linear(
    const float* __restrict__ x, const float* __restrict__ y,
    const float* __restrict__ W0, const float* __restrict__ W1,
    const float* __restrict__ W2, const float* __restrict__ cg,
    float* __restrict__ out)
{
  __shared__ __align__(16) uint16_t xs[480*32];    // 30720 B  bf16 [c][b]
  __shared__ __align__(16) uint16_t Tsh[179*40];   // 14320 B  bf16 [e][b], stride 40
  __shared__ __align__(16) float    ysm[9*32];     //  1152 B  f32  [c][b]
  __shared__ __align__(16) uint16_t Zs[300*32];    // 19200 B  bf16 [row][b]
  // total 65392 B

  const int tid = threadIdx.x;
  const int b0 = blockIdx.x * NB;

  // ---- stage x -> bf16 LDS, transposed [c][b] (gather reads, L1-absorbed) ----
  for (int idx = tid; idx < 480*32; idx += NT){
    const int c = idx >> 5, b = idx & 31;
    xs[c*32 + b] = (uint16_t)f2bf(x[(size_t)(b0+b)*480 + c]);
  }
  // ---- stage y (fp32, [c][b]) ----
  for (int idx = tid; idx < 9*32; idx += NT){
    const int c = idx % 9, b = idx / 9;
    ysm[c*32 + b] = y[(size_t)b0*9 + idx];
  }
  __syncthreads();

  // ---- build T[e][b] = sum_i2 cg * y  (bf16) ----
  for (int idx = tid; idx < 179*4; idx += NT){
    const int e = idx >> 2, tb = idx & 3;
    int p = 0;
    while (p+1 < 15 && e >= P_TSTART[p+1]) ++p;
    const int r = e - P_TSTART[p];
    const int d3 = P_D3[p], d2 = P_D2[p];
    const int i1 = r / d3, j3 = r - (r/d3)*d3;
    const float* cgp = cg + P_CGOFF[p] + (i1*d2)*d3 + j3;
    float t[8] = {0.f,0.f,0.f,0.f,0.f,0.f,0.f,0.f};
    for (int i2 = 0; i2 < d2; ++i2){
      const float c = cgp[i2*d3];
      const float* yp = &ysm[(P_YOFF[p]+i2)*32 + tb*8];
      float4 a = *(const float4*)yp;
      float4 b4 = *(const float4*)(yp+4);
      t[0]+=c*a.x;  t[1]+=c*a.y;  t[2]+=c*a.z;  t[3]+=c*a.w;
      t[4]+=c*b4.x; t[5]+=c*b4.y; t[6]+=c*b4.z; t[7]+=c*b4.w;
    }
    uint4 o;
    o.x = pk2(t[0],t[1]); o.y = pk2(t[2],t[3]);
    o.z = pk2(t[4],t[5]); o.w = pk2(t[6],t[7]);
    *(uint4*)&Tsh[e*40 + tb*8] = o;
  }
  __syncthreads();

  run_group<0>(W0, out, b0, tid, xs, Tsh, Zs);
  run_group<1>(W1, out, b0, tid, xs, Tsh, Zs);
  run_group<2>(W2, out, b0, tid, xs, Tsh, Zs);
}

extern "C" void kernel_launch(void* const* d_in, const int* in_sizes, int n_in,
                              void* d_out, int out_size, void* d_ws, size_t ws_size,
                              hipStream_t stream)
{
  const float* x  = (const float*)d_in[0];
  const float* y  = (const float*)d_in[1];
  const float* W0 = (const float*)d_in[2];
  const float* W1 = (const float*)d_in[3];
  const float* W2 = (const float*)d_in[4];
  float* out = (float*)d_out;
  float* cg  = (float*)d_ws;   // 615 floats

  hipLaunchKernelGGL(cg_setup, dim3(3), dim3(256), 0, stream, cg);
  hipLaunchKernelGGL(tp_linear, dim3(NBATCH/NB), dim3(NT), 0, stream,
                     x, y, W0, W1, W2, cg, out);
}

// Round 3
// 208.130 us; speedup vs baseline: 1.9592x; 1.4510x over previous
//
#include <hip/hip_runtime.h>
#include <math.h>
#include <stdint.h>

#define NBATCH 16384
#define NB 32
#define NT 256
#define NBLOCKS (NBATCH/NB)

typedef float  f32x4 __attribute__((ext_vector_type(4)));
typedef short  s16x8 __attribute__((ext_vector_type(8)));

// ---------------- path metadata (validated rounds 1-2) ----------------
__device__ const int P_CGOFF[15] = {0,1,10,35,44,53,80,125,170,245,270,315,390,415,490};
__device__ const int P_D2[15]    = {1,3,5,3,1,3,5,3,5,5,3,5,1,3,5};
__device__ const int P_D3[15]    = {1,1,1,3,3,3,3,3,3,5,5,5,5,5,5};
__device__ const int P_TSTART[15]= {0,1,4,9,12,21,30,39,54,69,74,89,104,129,154};
__device__ const int P_YOFF[15]  = {0,1,4,1,0,1,4,1,4,4,1,4,0,1,4};

__device__ const int CG_D1[15] = {1,3,5,1,3,3,3,5,5,1,3,3,5,5,5};
__device__ const int CG_L1[15] = {0,1,2,0,1,1,1,2,2,0,1,1,2,2,2};
__device__ const int CG_L2[15] = {0,1,2,1,0,1,2,1,2,2,1,2,0,1,2};
__device__ const int CG_L3[15] = {0,0,0,1,1,1,1,1,1,2,2,2,2,2,2};

// ---------------- CG math (validated round 1) ----------------
__device__ double dfact(int n){ double r=1.0; for(int i=2;i<=n;++i) r*=(double)i; return r; }

__device__ double su2_cg(int j1,int j2,int j3,int m1,int m2,int m3){
  if (m1+m2 != m3) return 0.0;
  double pref = sqrt((double)(2*j3+1)*dfact(j1+j2-j3)*dfact(j1-j2+j3)*dfact(-j1+j2+j3)/dfact(j1+j2+j3+1));
  pref *= sqrt(dfact(j3+m3)*dfact(j3-m3)*dfact(j1-m1)*dfact(j1+m1)*dfact(j2-m2)*dfact(j2+m2));
  double s=0.0;
  for(int v=0;v<=j1+j2-j3;++v){
    int a=j1+j2-j3-v, b=j1-m1-v, c=j2+m2-v, d=j3-j2+m1+v, e=j3-j1-m2+v;
    if(a<0||b<0||c<0||d<0||e<0) continue;
    double term = 1.0/(dfact(v)*dfact(a)*dfact(b)*dfact(c)*dfact(d)*dfact(e));
    s += (v&1)? -term : term;
  }
  return pref*s;
}

__device__ void qval(int l,int r,int c,double* qr,double* qi){
  int m = r - l;
  const double is2 = 0.70710678118654752440;
  double br=0.0, bi=0.0;
  if (m<0){
    if (c == l - m) br = is2;
    else if (c == l + m) bi = -is2;
  } else if (m==0){
    if (c==l) br = 1.0;
  } else {
    double sg = (m&1)? -1.0 : 1.0;
    if (c == l + m) br = sg*is2;
    else if (c == l - m) bi = sg*is2;
  }
  if (l==1){ double nr = bi, ni = -br; br=nr; bi=ni; }
  else if (l==2){ br=-br; bi=-bi; }
  *qr=br; *qi=bi;
}

// ---------------- bf16 helpers ----------------
__device__ __forceinline__ uint32_t f2bf(float f){
  uint32_t u = __float_as_uint(f);
  return (u + 0x7fffu + ((u>>16)&1u)) >> 16;   // RNE
}
__device__ __forceinline__ float bf2f(uint32_t v){ return __uint_as_float(v << 16); }
__device__ __forceinline__ uint32_t pk2(float a, float b){ return (f2bf(b)<<16) | f2bf(a); }

template<int I> struct IC { static constexpr int v = I; };

// ---------------- prep: CG table + bf16-transposed W into d_ws ----------------
// ws layout: [0,2460)   cg f32 (615)
//            [2560, +57344)  Wt0 bf16 [n=128][K=224]
//            then Wt1 bf16 [64][384], Wt2 bf16 [32][352]
__global__ void prep(const float* __restrict__ W0, const float* __restrict__ W1,
                     const float* __restrict__ W2, float* __restrict__ ws)
{
  int t = blockIdx.x*blockDim.x + threadIdx.x;
  if (t < 615){
    int p = 0;
    while (p+1 < 15 && t >= P_CGOFF[p+1]) ++p;
    int r = t - P_CGOFF[p];
    int d2 = P_D2[p], d3 = P_D3[p];
    int i1 = r/(d2*d3); int rem = r - i1*(d2*d3); int i2 = rem/d3; int i3 = rem - i2*d3;
    int l1=CG_L1[p], l2=CG_L2[p], l3=CG_L3[p];
    double acc = 0.0;
    for (int i=0;i<=2*l1;++i){
      for (int k=0;k<=2*l2;++k){
        int n = i + k - l1 - l2 + l3;
        if (n<0 || n>2*l3) continue;
        double c = su2_cg(l1,l2,l3, i-l1, k-l2, n-l3);
        if (c==0.0) continue;
        double q1r,q1i,q2r,q2i,q3r,q3i;
        qval(l1,i,i1,&q1r,&q1i);
        qval(l2,k,i2,&q2r,&q2i);
        qval(l3,n,i3,&q3r,&q3i);
        q3i = -q3i;
        double ar = q1r*q2r - q1i*q2i;
        double ai = q1r*q2i + q1i*q2r;
        acc += (ar*q3r - ai*q3i)*c;
      }
    }
    ws[t] = (float)acc;
  }
  if (t < 64512){
    uint16_t* wt = (uint16_t*)((char*)ws + 2560);
    float v;
    if (t < 28672){                     // Wt0[n][u], n<128, K=224
      int n = t / 224, u = t - n*224;
      v = W0[u*128 + n];
    } else if (t < 53248){              // Wt1[n][u], n<64, K=384
      int t2 = t - 28672;
      int n = t2 / 384, u = t2 - n*384;
      v = W1[u*64 + n];
    } else {                            // Wt2[n][u], n<32, K=352
      int t3 = t - 53248;
      int n = t3 / 352, u = t3 - n*352;
      v = W2[u*32 + n];
    }
    wt[t] = (uint16_t)f2bf(v);
  }
}

// ---------------- per-group compile-time metadata ----------------
template<int G> struct GM;
template<> struct GM<0>{
  static constexpr int K=224,N=128,D3=1,OB=0,NSEG=3,NCH=1,PITCH=232,MROWS=32;
  static constexpr int CKS[1]={224};
  static constexpr int U0[4]={0,128,192,224};
  static constexpr int D1S[3]={1,3,5};
  static constexpr int TS0[3]={0,1,4};
  static constexpr int XO[3]={0,128,320};
  static constexpr int NT_W=2, MT_W=2;      // wave: 2 n-tiles x 2 m-tiles
  static constexpr float SC = 0.066815310478f;  // 1/sqrt(224)
  static constexpr int WOFF=0;
};
template<> struct GM<1>{
  static constexpr int K=384,N=64,D3=3,OB=128,NSEG=6,NCH=3,PITCH=136,MROWS=96;
  static constexpr int CKS[3]={128,128,128};
  static constexpr int U0[7]={0,128,192,256,320,352,384};
  static constexpr int D1S[6]={1,3,3,3,5,5};
  static constexpr int TS0[6]={9,12,21,30,39,54};
  static constexpr int XO[6]={0,128,128,128,320,320};
  static constexpr int NT_W=1, MT_W=6;      // wave: 1 n-tile x 6 m-tiles
  static constexpr float SC = 0.051031036308f;  // 1/sqrt(384)
  static constexpr int WOFF=28672;
};
template<> struct GM<2>{
  static constexpr int K=352,N=32,D3=5,OB=320,NSEG=6,NCH=4,PITCH=104,MROWS=160;
  static constexpr int CKS[4]={96,96,96,64};
  static constexpr int U0[7]={0,128,192,256,288,320,352};
  static constexpr int D1S[6]={1,3,3,5,5,5};
  static constexpr int TS0[6]={69,74,89,104,129,154};
  static constexpr int XO[6]={0,128,128,320,320,320};
  static constexpr int NT_W=1, MT_W=5;      // wave: 1 n-tile x 5 m-tiles (2x2 wave grid)
  static constexpr float SC = 0.053300179089f;  // 1/sqrt(352)
  static constexpr int WOFF=53248;
};

// ---------------- per-group fused TP(Z-build) + MFMA Linear ----------------
template<int G>
__device__ __forceinline__ void run_group(const uint16_t* __restrict__ wt_all,
                                          const float* __restrict__ x,
                                          float* __restrict__ out, int b0, int tid,
                                          const uint16_t* Tsh, uint16_t* Zs)
{
  using M = GM<G>;
  constexpr int D3 = M::D3;
  const int lane = tid & 63;
  const int w    = tid >> 6;
  const int ln   = lane & 15;        // n/m index within tile
  const int hi8  = (lane >> 4) * 8;  // k-octet offset within 32

  int nt0, mt0;
  if constexpr (G == 0){ nt0 = 2*w; mt0 = 0; }
  else if constexpr (G == 1){ nt0 = w; mt0 = 0; }
  else { nt0 = w & 1; mt0 = 5*(w >> 1); }

  const short* wt = (const short*)(wt_all + M::WOFF);

  f32x4 acc[M::NT_W * M::MT_W];
  #pragma unroll
  for (int i = 0; i < M::NT_W*M::MT_W; ++i) acc[i] = (f32x4){0.f,0.f,0.f,0.f};

  int u0 = 0;
  #pragma unroll
  for (int ch = 0; ch < M::NCH; ++ch){
    constexpr int KCMAX = M::CKS[0];
    const int Kc  = M::CKS[ch];
    const int OPC = Kc >> 3;        // u-octets per row
    const int KS  = Kc >> 5;        // MFMA k-steps

    // ---- Phase A: Z[m][k-local] bf16, thread = (m-row, u-octet) ----
    for (int idx = tid; idx < M::MROWS*OPC; idx += NT){
      const int m   = idx / OPC;
      const int oct = idx - m*OPC;
      const int b   = m / D3;
      const int i3  = m - b*D3;
      const int u   = u0 + oct*8;
      int s = 0;
      #pragma unroll
      for (int t = 0; t < M::NSEG-1; ++t) s += (u >= M::U0[t+1]);
      const int d1 = M::D1S[s];
      const int cb = M::XO[s] + (u - M::U0[s])*d1;
      const float* xg = x + (size_t)(b0+b)*480 + cb;
      const int ts = M::TS0[s] + i3;

      auto body = [&](auto D1T){
        constexpr int D1 = decltype(D1T)::v;
        float tv[D1];
        #pragma unroll
        for (int i1 = 0; i1 < D1; ++i1)
          tv[i1] = bf2f(Tsh[(ts + i1*D3)*40 + b]);
        float xv[8*D1];
        #pragma unroll
        for (int j = 0; j < 8*D1; ++j) xv[j] = xg[j];
        uint32_t o[4];
        #pragma unroll
        for (int q = 0; q < 8; q += 2){
          float z0 = 0.f, z1 = 0.f;
          #pragma unroll
          for (int i1 = 0; i1 < D1; ++i1){
            z0 += xv[q*D1+i1]     * tv[i1];
            z1 += xv[(q+1)*D1+i1] * tv[i1];
          }
          o[q>>1] = pk2(z0, z1);
        }
        *(uint4*)&Zs[m*M::PITCH + oct*8] = make_uint4(o[0],o[1],o[2],o[3]);
      };
      if (d1 == 1) body(IC<1>{}); else if (d1 == 3) body(IC<3>{}); else body(IC<5>{});
    }
    __syncthreads();

    // ---- Phase B: MFMA ----
    {
      #pragma unroll
      for (int nti = 0; nti < M::NT_W; ++nti){
        const int n = (nt0 + nti)*16 + ln;
        const short* wrow = wt + n*M::K + u0 + hi8;
        s16x8 Bf[KCMAX/32];
        #pragma unroll
        for (int t = 0; t < KCMAX/32; ++t)
          if (t < KS) Bf[t] = *(const s16x8*)(wrow + t*32);
        #pragma unroll
        for (int mti = 0; mti < M::MT_W; ++mti){
          const uint16_t* zrow = Zs + ((mt0+mti)*16 + ln)*M::PITCH + hi8;
          #pragma unroll
          for (int t = 0; t < KCMAX/32; ++t){
            if (t < KS){
              s16x8 Af = *(const s16x8*)(zrow + t*32);
              acc[nti*M::MT_W + mti] =
                __builtin_amdgcn_mfma_f32_16x16x32_bf16(Af, Bf[t], acc[nti*M::MT_W + mti], 0, 0, 0);
            }
          }
        }
      }
    }
    __syncthreads();
    u0 += Kc;
  }

  // ---- epilogue: C/D layout col=lane&15, row=(lane>>4)*4+r (m89-verified) ----
  #pragma unroll
  for (int nti = 0; nti < M::NT_W; ++nti){
    const int v = (nt0 + nti)*16 + ln;
    #pragma unroll
    for (int mti = 0; mti < M::MT_W; ++mti){
      f32x4 a = acc[nti*M::MT_W + mti];
      #pragma unroll
      for (int r = 0; r < 4; ++r){
        const int row = (mt0 + mti)*16 + (hi8 >> 1) + r;   // (lane>>4)*4 + r
        const int b   = row / D3;
        const int i3  = row - b*D3;
        out[(size_t)(b0 + b)*480 + M::OB + v*D3 + i3] = a[r]*M::SC;
      }
    }
  }
}

// ---------------- main fused kernel ----------------
__global__ __launch_bounds__(NT, 3) void tp_linear(
    const float* __restrict__ x, const float* __restrict__ y,
    const float* __restrict__ ws, float* __restrict__ out)
{
  __shared__ __align__(16) uint16_t Tsh[179*40];   // 14320 B  bf16 T[e][b]
  __shared__ __align__(16) float    ysm[9*32];     //  1152 B
  __shared__ __align__(16) uint16_t Zs[160*104];   // 33280 B  bf16 Z[m][k-local]
  // total 48752 B -> 3 blocks/CU

  const int tid = threadIdx.x;
  const int b0 = blockIdx.x * NB;
  const float* cg = ws;
  const uint16_t* wt_all = (const uint16_t*)((const char*)ws + 2560);

  // ---- stage y ----
  for (int idx = tid; idx < 9*32; idx += NT){
    const int c = idx % 9, b = idx / 9;
    ysm[c*32 + b] = y[(size_t)b0*9 + idx];
  }
  __syncthreads();

  // ---- build T[e][b] = sum_i2 cg * y  (bf16) — validated round 2 ----
  for (int idx = tid; idx < 179*4; idx += NT){
    const int e = idx >> 2, tb = idx & 3;
    int p = 0;
    while (p+1 < 15 && e >= P_TSTART[p+1]) ++p;
    const int r = e - P_TSTART[p];
    const int d3 = P_D3[p], d2 = P_D2[p];
    const int i1 = r / d3, j3 = r - (r/d3)*d3;
    const float* cgp = cg + P_CGOFF[p] + (i1*d2)*d3 + j3;
    float t[8] = {0.f,0.f,0.f,0.f,0.f,0.f,0.f,0.f};
    for (int i2 = 0; i2 < d2; ++i2){
      const float c = cgp[i2*d3];
      const float* yp = &ysm[(P_YOFF[p]+i2)*32 + tb*8];
      float4 a = *(const float4*)yp;
      float4 b4 = *(const float4*)(yp+4);
      t[0]+=c*a.x;  t[1]+=c*a.y;  t[2]+=c*a.z;  t[3]+=c*a.w;
      t[4]+=c*b4.x; t[5]+=c*b4.y; t[6]+=c*b4.z; t[7]+=c*b4.w;
    }
    uint4 o;
    o.x = pk2(t[0],t[1]); o.y = pk2(t[2],t[3]);
    o.z = pk2(t[4],t[5]); o.w = pk2(t[6],t[7]);
    *(uint4*)&Tsh[e*40 + tb*8] = o;
  }
  __syncthreads();

  run_group<0>(wt_all, x, out, b0, tid, Tsh, Zs);
  run_group<1>(wt_all, x, out, b0, tid, Tsh, Zs);
  run_group<2>(wt_all, x, out, b0, tid, Tsh, Zs);
}

extern "C" void kernel_launch(void* const* d_in, const int* in_sizes, int n_in,
                              void* d_out, int out_size, void* d_ws, size_t ws_size,
                              hipStream_t stream)
{
  const float* x  = (const float*)d_in[0];
  const float* y  = (const float*)d_in[1];
  const float* W0 = (const float*)d_in[2];
  const float* W1 = (const float*)d_in[3];
  const float* W2 = (const float*)d_in[4];
  float* out = (float*)d_out;
  float* ws  = (float*)d_ws;   // 2560 B cg + 129024 B bf16 W^T

  hipLaunchKernelGGL(prep, dim3(253), dim3(256), 0, stream, W0, W1, W2, ws);
  hipLaunchKernelGGL(tp_linear, dim3(NBLOCKS), dim3(NT), 0, stream, x, y, ws, out);
}

// Round 4
// 136.697 us; speedup vs baseline: 2.9831x; 1.5226x over previous
//
#include <hip/hip_runtime.h>
#include <math.h>
#include <stdint.h>

#define NBATCH 16384
#define MB 16
#define NT 256
#define NBLOCKS (NBATCH/MB)
#define WT_BYTE_OFF 2560
#define XPITCH 488   // bf16 elements per batch row in LDS (480 + 8 pad, 16B-multiple)

typedef float  f32x4 __attribute__((ext_vector_type(4)));
typedef short  s16x8 __attribute__((ext_vector_type(8)));

// ---------------- path metadata (validated rounds 1-3) ----------------
__device__ const int P_CGOFF[15] = {0,1,10,35,44,53,80,125,170,245,270,315,390,415,490};
__device__ const int P_D2[15]    = {1,3,5,3,1,3,5,3,5,5,3,5,1,3,5};
__device__ const int P_D3[15]    = {1,1,1,3,3,3,3,3,3,5,5,5,5,5,5};
__device__ const int P_TSTART[15]= {0,1,4,9,12,21,30,39,54,69,74,89,104,129,154};
__device__ const int P_YOFF[15]  = {0,1,4,1,0,1,4,1,4,4,1,4,0,1,4};
__device__ const int CG_L1[15] = {0,1,2,0,1,1,1,2,2,0,1,1,2,2,2};
__device__ const int CG_L2[15] = {0,1,2,1,0,1,2,1,2,2,1,2,0,1,2};
__device__ const int CG_L3[15] = {0,0,0,1,1,1,1,1,1,2,2,2,2,2,2};

// 15 weight segments: (group, wbase, mul(shift), u0-in-group)
__device__ const int   SEG_WB[15] = {0,16384,24576, 28672,36864,40960,45056,49152,51200,
                                     53248,57344,59392,61440,62464,63488};
__device__ const int   SEG_SH[15] = {7,6,5, 7,6,6,6,5,5, 7,6,6,5,5,5};
__device__ const int   SEG_U0[15] = {0,128,192, 0,128,192,256,320,352, 0,128,192,256,288,320};
__device__ const int   SEG_G[15]  = {0,0,0, 1,1,1,1,1,1, 2,2,2,2,2,2};
__device__ const float SEG_SC[3]  = {0.066815310478f, 0.051031036308f, 0.053300179089f};

// ---------------- f32 CG math (factorials <=12! are exact in f32) ----------------
__device__ const float FCT[13] = {1.f,1.f,2.f,6.f,24.f,120.f,720.f,5040.f,40320.f,
                                  362880.f,3628800.f,39916800.f,479001600.f};

__device__ float su2f(int j1,int j2,int j3,int m1,int m2,int m3){
  float pref = sqrtf((float)(2*j3+1)*FCT[j1+j2-j3]*FCT[j1-j2+j3]*FCT[-j1+j2+j3]/FCT[j1+j2+j3+1]);
  pref *= sqrtf(FCT[j3+m3]*FCT[j3-m3]*FCT[j1-m1]*FCT[j1+m1]*FCT[j2-m2]*FCT[j2+m2]);
  float s = 0.f;
  for (int v=0; v<=j1+j2-j3; ++v){
    int a=j1+j2-j3-v, b=j1-m1-v, c=j2+m2-v, d=j3-j2+m1+v, e=j3-j1-m2+v;
    if (a<0||b<0||c<0||d<0||e<0) continue;
    float term = 1.f/(FCT[v]*FCT[a]*FCT[b]*FCT[c]*FCT[d]*FCT[e]);
    s += (v&1) ? -term : term;
  }
  return pref*s;
}

__device__ void qvalf(int l,int r,int c,float* qr,float* qi){
  int m = r - l;
  const float is2 = 0.70710678118654752440f;
  float br=0.f, bi=0.f;
  if (m<0){
    if (c == l - m) br = is2;
    else if (c == l + m) bi = -is2;
  } else if (m==0){
    if (c==l) br = 1.f;
  } else {
    float sg = (m&1)? -1.f : 1.f;
    if (c == l + m) br = sg*is2;
    else if (c == l - m) bi = sg*is2;
  }
  if (l==1){ float nr = bi, ni = -br; br=nr; bi=ni; }   // *(-i)
  else if (l==2){ br=-br; bi=-bi; }                     // *(-i)^2
  *qr=br; *qi=bi;
}

// ---------------- bf16 helpers ----------------
__device__ __forceinline__ uint32_t f2bf(float f){
  uint32_t u = __float_as_uint(f);
  return (u + 0x7fffu + ((u>>16)&1u)) >> 16;   // RNE
}
__device__ __forceinline__ float bf2f(uint32_t v){ return __uint_as_float(v << 16); }

// ---------------- prep: Wt pack (bf16, scale folded) + CG (f32 atomic) ----------------
// ws layout: [0,2460) cg f32; [2560, 2560+129024) Wt bf16 [seg][v][u1]
__global__ void prep(const float* __restrict__ W0, const float* __restrict__ W1,
                     const float* __restrict__ W2, float* __restrict__ ws)
{
  int t = blockIdx.x*NT + threadIdx.x;
  if (t < 64512){
    uint16_t* wt = (uint16_t*)((char*)ws + WT_BYTE_OFF);
    int j = 0;
    while (j < 14 && t >= SEG_WB[j+1]) ++j;
    int idx = t - SEG_WB[j];
    int sh = SEG_SH[j];
    int v  = idx >> sh, u1 = idx & ((1<<sh)-1);
    int g  = SEG_G[j];
    int N  = (g==0)?128:(g==1)?64:32;
    const float* Wsrc = (g==0)?W0:(g==1)?W1:W2;
    wt[t] = (uint16_t)f2bf(Wsrc[(SEG_U0[j]+u1)*N + v] * SEG_SC[g]);
  }
  int t2 = t - 64512;
  if (t2 >= 0 && t2 < 615*25){
    int e = t2/25, ik = t2 - e*25;
    int i = ik/5, k = ik - (ik/5)*5;
    int p = 0;
    while (p < 14 && e >= P_CGOFF[p+1]) ++p;
    int r = e - P_CGOFF[p];
    int d2 = P_D2[p], d3 = P_D3[p];
    int i1 = r/(d2*d3); int rem = r - i1*(d2*d3);
    int i2 = rem/d3;    int i3 = rem - i2*d3;
    int l1 = CG_L1[p], l2 = CG_L2[p], l3 = CG_L3[p];
    if (i <= 2*l1 && k <= 2*l2){
      int n = i + k - l1 - l2 + l3;
      if (n >= 0 && n <= 2*l3){
        float c = su2f(l1,l2,l3, i-l1, k-l2, n-l3);
        if (c != 0.f){
          float q1r,q1i,q2r,q2i,q3r,q3i;
          qvalf(l1,i,i1,&q1r,&q1i);
          qvalf(l2,k,i2,&q2r,&q2i);
          qvalf(l3,n,i3,&q3r,&q3i);
          q3i = -q3i;                       // conj(Q3)
          float ar = q1r*q2r - q1i*q2i;
          float ai = q1r*q2i + q1i*q2r;
          float contrib = (ar*q3r - ai*q3i)*c;
          if (contrib != 0.f) atomicAdd(&ws[e], contrib);
        }
      }
    }
  }
}

// ---------------- per-group compile-time metadata ----------------
template<int G> struct GM;
template<> struct GM<0>{
  static constexpr int NS=3, D3=1, OB=0, NMT=2, NI3=1;
  static constexpr int MUL[3]={128,64,32};
  static constexpr int D1[3] ={1,3,5};
  static constexpr int XB[3] ={0,128,320};
  static constexpr int TS[3] ={0,1,4};
  static constexpr int WB[3] ={0,16384,24576};
};
template<> struct GM<1>{
  static constexpr int NS=6, D3=3, OB=128, NMT=1, NI3=3;
  static constexpr int MUL[6]={128,64,64,64,32,32};
  static constexpr int D1[6] ={1,3,3,3,5,5};
  static constexpr int XB[6] ={0,128,128,128,320,320};
  static constexpr int TS[6] ={9,12,21,30,39,54};
  static constexpr int WB[6] ={28672,36864,40960,45056,49152,51200};
};
template<> struct GM<2>{
  static constexpr int NS=6, D3=5, OB=320, NMT=1, NI3=3;
  static constexpr int MUL[6]={128,64,64,32,32,32};
  static constexpr int D1[6] ={1,3,3,5,5,5};
  static constexpr int XB[6] ={0,128,128,320,320,320};
  static constexpr int TS[6] ={69,74,89,104,129,154};
  static constexpr int WB[6] ={53248,57344,59392,61440,62464,63488};
};

// one segment: A=Wt (m=v), B=xp (n=batch), K=mul; T-contract into acc
template<int G, int S, int NMT, int NI3>
__device__ __forceinline__ void do_seg(const short* __restrict__ wt,
                                       const uint16_t* __restrict__ xp,
                                       const uint16_t* __restrict__ Tsh,
                                       f32x4 (&acc)[NMT][NI3],
                                       int ln, int koct, int mt0, int i3base, int ni3)
{
  using M = GM<G>;
  constexpr int MUL = M::MUL[S];
  constexpr int KS  = MUL >> 5;
  constexpr int D1  = M::D1[S];

  s16x8 Af[NMT][KS];
  #pragma unroll
  for (int mt = 0; mt < NMT; ++mt)
    #pragma unroll
    for (int kk = 0; kk < KS; ++kk)
      Af[mt][kk] = *(const s16x8*)(wt + M::WB[S] + ((mt0+mt)*16 + ln)*MUL + kk*32 + koct);

  #pragma unroll
  for (int i1 = 0; i1 < D1; ++i1){
    s16x8 Bf[KS];
    #pragma unroll
    for (int kk = 0; kk < KS; ++kk)
      Bf[kk] = *(const s16x8*)((const short*)xp + ln*XPITCH + M::XB[S] + i1*MUL + kk*32 + koct);
    #pragma unroll
    for (int mt = 0; mt < NMT; ++mt){
      f32x4 D = {0.f,0.f,0.f,0.f};
      #pragma unroll
      for (int kk = 0; kk < KS; ++kk)
        D = __builtin_amdgcn_mfma_f32_16x16x32_bf16(Af[mt][kk], Bf[kk], D, 0, 0, 0);
      #pragma unroll
      for (int j = 0; j < NI3; ++j){
        if (j < ni3){
          const int e = M::TS[S] + i1*M::D3 + i3base + j;
          const float tv = bf2f(Tsh[e*16 + ln]);
          acc[mt][j][0] += tv*D[0];
          acc[mt][j][1] += tv*D[1];
          acc[mt][j][2] += tv*D[2];
          acc[mt][j][3] += tv*D[3];
        }
      }
    }
  }
}

template<int G>
__device__ __forceinline__ void run_group(const short* __restrict__ wt,
                                          float* __restrict__ out, int b0, int tid,
                                          const uint16_t* __restrict__ Tsh,
                                          const uint16_t* __restrict__ xp)
{
  using M = GM<G>;
  const int lane = tid & 63, w = tid >> 6;
  const int ln   = lane & 15;          // A: m-index / B: n-index / D: col (=batch)
  const int koct = (lane >> 4) * 8;    // k-octet
  constexpr int NMT = M::NMT, NI3 = M::NI3;

  int mt0, i3base, ni3;
  if constexpr (G == 0){ mt0 = 2*w; i3base = 0; ni3 = 1; }
  else if constexpr (G == 1){ mt0 = w; i3base = 0; ni3 = 3; }
  else { mt0 = w >> 1; i3base = (w & 1)*3; ni3 = (w & 1) ? 2 : 3; }

  f32x4 acc[NMT][NI3];
  #pragma unroll
  for (int a = 0; a < NMT; ++a)
    #pragma unroll
    for (int b = 0; b < NI3; ++b) acc[a][b] = (f32x4){0.f,0.f,0.f,0.f};

  do_seg<G,0,NMT,NI3>(wt, xp, Tsh, acc, ln, koct, mt0, i3base, ni3);
  do_seg<G,1,NMT,NI3>(wt, xp, Tsh, acc, ln, koct, mt0, i3base, ni3);
  do_seg<G,2,NMT,NI3>(wt, xp, Tsh, acc, ln, koct, mt0, i3base, ni3);
  if constexpr (M::NS > 3){
    do_seg<G,(M::NS>3)?3:0,NMT,NI3>(wt, xp, Tsh, acc, ln, koct, mt0, i3base, ni3);
    do_seg<G,(M::NS>4)?4:0,NMT,NI3>(wt, xp, Tsh, acc, ln, koct, mt0, i3base, ni3);
    do_seg<G,(M::NS>5)?5:0,NMT,NI3>(wt, xp, Tsh, acc, ln, koct, mt0, i3base, ni3);
  }

  // ---- stores: D col=lane&15=batch, rows=(lane>>4)*4+r = v (r3-verified) ----
  const int rq = (lane >> 4) * 4;
  float* orow = out + (size_t)(b0 + ln)*480;
  if constexpr (G == 0){
    #pragma unroll
    for (int mt = 0; mt < NMT; ++mt){
      const int vb = (mt0+mt)*16 + rq;
      float4 st = make_float4(acc[mt][0][0], acc[mt][0][1], acc[mt][0][2], acc[mt][0][3]);
      *(float4*)(orow + vb) = st;            // cols v..v+3, 16B aligned
    }
  } else if constexpr (G == 1){
    const int vb = mt0*16 + rq;
    float buf[12];
    #pragma unroll
    for (int r = 0; r < 4; ++r)
      #pragma unroll
      for (int j = 0; j < 3; ++j) buf[r*3+j] = acc[0][j][r];
    float* p = orow + 128 + vb*3;            // 128+12k -> 16B aligned
    *(float4*)(p)   = make_float4(buf[0],buf[1],buf[2],buf[3]);
    *(float4*)(p+4) = make_float4(buf[4],buf[5],buf[6],buf[7]);
    *(float4*)(p+8) = make_float4(buf[8],buf[9],buf[10],buf[11]);
  } else {
    const int vb = mt0*16 + rq;
    #pragma unroll
    for (int r = 0; r < 4; ++r)
      #pragma unroll
      for (int j = 0; j < 3; ++j)
        if (j < ni3)
          orow[320 + (vb+r)*5 + i3base + j] = acc[0][j][r];
  }
}

// x column permutation: c -> o  (irrep-major: [l1][i1][u])
__device__ __forceinline__ int xmap(int c){
  if (c < 128) return c;
  if (c < 320){ int t = c - 128; int u = t/3; int i1 = t - u*3; return 128 + i1*64 + u; }
  int t = c - 320; int u = t/5; int i1 = t - u*5; return 320 + i1*32 + u;
}

// ---------------- main fused kernel ----------------
__global__ __launch_bounds__(NT) void tp_linear(
    const float* __restrict__ x, const float* __restrict__ y,
    const float* __restrict__ ws, float* __restrict__ out)
{
  __shared__ __align__(16) uint16_t xp[MB*XPITCH];   // 15616 B  bf16, permuted [b][o]
  __shared__ __align__(16) uint16_t Tsh[179*16];     //  5728 B  bf16 T[e][b]
  __shared__ __align__(16) float    cgs[616];        //  2464 B
  __shared__ __align__(16) float    ysm[MB*12];      //   768 B
  // total ~24.6 KB

  const int tid = threadIdx.x;
  const int b0 = blockIdx.x * MB;
  const short* wt = (const short*)((const char*)ws + WT_BYTE_OFF);

  // ---- stage cg, y, x(permuted bf16) ----
  for (int i = tid; i < 615; i += NT) cgs[i] = ws[i];
  for (int i = tid; i < MB*9; i += NT){
    int b = i/9, c = i - b*9;
    ysm[b*12 + c] = y[(size_t)b0*9 + i];
  }
  for (int i = tid; i < MB*120; i += NT){
    int b = i/120, q = i - b*120;
    float4 v = ((const float4*)(x + (size_t)(b0+b)*480))[q];
    int c = q*4;
    xp[b*XPITCH + xmap(c)]   = (uint16_t)f2bf(v.x);
    xp[b*XPITCH + xmap(c+1)] = (uint16_t)f2bf(v.y);
    xp[b*XPITCH + xmap(c+2)] = (uint16_t)f2bf(v.z);
    xp[b*XPITCH + xmap(c+3)] = (uint16_t)f2bf(v.w);
  }
  __syncthreads();

  // ---- T[e][b] = sum_i2 cg*y (bf16) — formula validated r2/r3 ----
  for (int i = tid; i < 179*16; i += NT){
    const int e = i >> 4, b = i & 15;
    int p = 0;
    while (p < 14 && e >= P_TSTART[p+1]) ++p;
    const int r = e - P_TSTART[p];
    const int d3 = P_D3[p], d2 = P_D2[p];
    const int i1 = r / d3, j3 = r - (r/d3)*d3;
    const float* cgp = cgs + P_CGOFF[p] + (i1*d2)*d3 + j3;
    const float* yp  = ysm + b*12 + P_YOFF[p];
    float t = 0.f;
    for (int i2 = 0; i2 < d2; ++i2) t += cgp[i2*d3]*yp[i2];
    Tsh[e*16 + b] = (uint16_t)f2bf(t);
  }
  __syncthreads();

  // ---- 3 groups, no further barriers (xp/Tsh read-only from here) ----
  run_group<0>(wt, out, b0, tid, Tsh, xp);
  run_group<1>(wt, out, b0, tid, Tsh, xp);
  run_group<2>(wt, out, b0, tid, Tsh, xp);
}

extern "C" void kernel_launch(void* const* d_in, const int* in_sizes, int n_in,
                              void* d_out, int out_size, void* d_ws, size_t ws_size,
                              hipStream_t stream)
{
  const float* x  = (const float*)d_in[0];
  const float* y  = (const float*)d_in[1];
  const float* W0 = (const float*)d_in[2];
  const float* W1 = (const float*)d_in[3];
  const float* W2 = (const float*)d_in[4];
  float* out = (float*)d_out;
  float* ws  = (float*)d_ws;   // 2460 B cg (atomic, zero-init) + bf16 Wt at +2560

  hipMemsetAsync(d_ws, 0, 2464, stream);                       // cg accumulators
  hipLaunchKernelGGL(prep, dim3(313), dim3(NT), 0, stream, W0, W1, W2, ws);
  hipLaunchKernelGGL(tp_linear, dim3(NBLOCKS), dim3(NT), 0, stream, x, y, ws, out);
}